// Round 4
// baseline (1646.075 us; speedup 1.0000x reference)
//
#include <hip/hip_runtime.h>
#include <hip/hip_bf16.h>

// GRU forward v4 — weights in AGPRs.
//   Rounds 2-3 lesson: the VGPR allocator refuses to keep >=128 VGPRs of
//   loop-invariant weights live (remat/spill -> ~2us/step of L2 reload),
//   even with launch_bounds and "+v" pins. v4 parks Hr,Hz in the AGPR file
//   (256 AGPRs, "+a"-pinned named scalars; gfx950 MFMA reads B from AGPR
//   directly) and Hg in 128 pinned VGPRs. amdgpu_waves_per_eu(1,1) gives the
//   512-reg combined budget (256 thr, 1 wave/SIMD).
//   Pre-gates (x@W+b, f16 D-frags, precomputed in ws) stream through a 48KB
//   LDS double buffer via global_load_lds (no VGPR cost), vmcnt-gated.

typedef _Float16 f16;
typedef _Float16 half8 __attribute__((ext_vector_type(8)));
typedef float floatx4 __attribute__((ext_vector_type(4)));

#define MFMA16(a, b, c) __builtin_amdgcn_mfma_f32_16x16x32_f16((a), (b), (c), 0, 0, 0)

// ---- workspace layout (bytes) ----
#define WTAB_OFF   0u          // W frags  [g3][nt16][ktx2][lane64][16B]      = 98304
#define RZG_OFF    98304u      // H frags  [tid256][g3][nti4][kt8][16B]       = 393216
#define PRE_OFF    491520u     // pre-gates [bid 8176][g3][tid256][32B]       = 200933376
#define WS_NEED    (491520ull + 200933376ull)

typedef const __attribute__((address_space(1))) unsigned int* gp1;
typedef __attribute__((address_space(3))) unsigned int* lp3;

// =====================================================================
// prep: weight-fragment tables (30720 half8)
// =====================================================================
__global__ void gru_wprep(const float* __restrict__ Wr, const float* __restrict__ Wz,
                          const float* __restrict__ Wg, const float* __restrict__ Hr,
                          const float* __restrict__ Hz, const float* __restrict__ Hg,
                          f16* __restrict__ ws) {
    int idx = blockIdx.x * 256 + threadIdx.x;   // 0..30719
    if (idx >= 30720) return;
    const float* src;
    int col, k0;
    f16* dst;
    if (idx < 6144) {                            // Wtab: ((g*16+nt)*2+ktx)*64+lane
        int lane = idx & 63, ktx = (idx >> 6) & 1, nt = (idx >> 7) & 15, g = idx >> 11;
        src = (g == 0) ? Wr : (g == 1) ? Wz : Wg;
        col = nt * 16 + (lane & 15);
        k0  = ktx * 32 + (lane >> 4) * 8;
        dst = ws + WTAB_OFF / 2 + (size_t)idx * 8;
    } else {                                     // RZG: tid*96 + g*32 + nti*8 + kt
        int local = idx - 6144;                  // 0..24575
        int kt = local & 7, nti = (local >> 3) & 3;
        int rest = local >> 5;
        int g = rest % 3, tid = rest / 3;
        int l = tid & 63;
        src = (g == 0) ? Hr : (g == 1) ? Hz : Hg;
        col = ((tid >> 6) * 4 + nti) * 16 + (l & 15);
        k0  = kt * 32 + (l >> 4) * 8;
        dst = ws + RZG_OFF / 2 + (size_t)local * 8;
    }
    half8 v;
#pragma unroll
    for (int i = 0; i < 8; ++i) v[i] = (f16)src[(size_t)(k0 + i) * 256 + col];
    *(half8*)dst = v;
}

// =====================================================================
// prep: pre-gates  pre[bid][g][tid][32B] = (x_t @ W_g + b_g) D-frags, f16
// =====================================================================
__global__ void __launch_bounds__(256)
gru_gates(const float* __restrict__ x, const float* __restrict__ br,
          const float* __restrict__ bz, const float* __restrict__ bg,
          f16* __restrict__ ws) {
    const int bid = blockIdx.x;                  // t*16 + blk, t in [0,511)
    const int t = bid >> 4, blk = bid & 15;
    const int tid = threadIdx.x, w = tid >> 6, l = tid & 63;
    const int cl = l & 15, rq = l >> 4;

    half8 xa[2];
    const float* xr = x + (size_t)(blk * 16 + cl) * 32768 + (size_t)t * 64 + rq * 8;
#pragma unroll
    for (int ktx = 0; ktx < 2; ++ktx) {
        float4 a = *(const float4*)(xr + ktx * 32);
        float4 b = *(const float4*)(xr + ktx * 32 + 4);
        half8 v;
        v[0] = (f16)a.x; v[1] = (f16)a.y; v[2] = (f16)a.z; v[3] = (f16)a.w;
        v[4] = (f16)b.x; v[5] = (f16)b.y; v[6] = (f16)b.z; v[7] = (f16)b.w;
        xa[ktx] = v;
    }

    const half8* Wt = (const half8*)(ws + WTAB_OFF / 2);
    floatx4 acc[3][4];
#pragma unroll
    for (int g = 0; g < 3; ++g)
#pragma unroll
        for (int nti = 0; nti < 4; ++nti) {
            int col = (w * 4 + nti) * 16 + cl;
            float b = (g == 0 ? br : g == 1 ? bz : bg)[col];
            acc[g][nti] = (floatx4){b, b, b, b};
        }
#pragma unroll
    for (int g = 0; g < 3; ++g)
#pragma unroll
        for (int nti = 0; nti < 4; ++nti) {
            int nt = w * 4 + nti;
#pragma unroll
            for (int ktx = 0; ktx < 2; ++ktx)
                acc[g][nti] = MFMA16(xa[ktx], Wt[(size_t)((g * 16 + nt) * 2 + ktx) * 64 + l],
                                     acc[g][nti]);
        }

    // store 2 half8 per gate: elem q=c*8+e -> nti=q>>2, j=q&3
    half8* preb = (half8*)(ws + PRE_OFF / 2);
#pragma unroll
    for (int g = 0; g < 3; ++g) {
        half8 v0, v1;
#pragma unroll
        for (int e = 0; e < 8; ++e) {
            v0[e] = (f16)acc[g][e >> 2][e & 3];
            v1[e] = (f16)acc[g][2 + (e >> 2)][e & 3];
        }
        size_t base = ((size_t)(bid * 3 + g) * 256 + tid) * 2;
        preb[base]     = v0;
        preb[base + 1] = v1;
    }
}

// =====================================================================
// scan v4: 16 WGs x 256 threads, 1 wave/SIMD, weights in AGPR+VGPR
// =====================================================================

// load one kt-slice of weights as NAMED scalars; pin Hr,Hz->AGPR, Hg->VGPR
#define WLOAD(kt) \
    half8 hr_##kt##_0 = tab[0*32 + 0*8 + kt], hr_##kt##_1 = tab[0*32 + 1*8 + kt], \
          hr_##kt##_2 = tab[0*32 + 2*8 + kt], hr_##kt##_3 = tab[0*32 + 3*8 + kt]; \
    half8 hz_##kt##_0 = tab[1*32 + 0*8 + kt], hz_##kt##_1 = tab[1*32 + 1*8 + kt], \
          hz_##kt##_2 = tab[1*32 + 2*8 + kt], hz_##kt##_3 = tab[1*32 + 3*8 + kt]; \
    half8 hg_##kt##_0 = tab[2*32 + 0*8 + kt], hg_##kt##_1 = tab[2*32 + 1*8 + kt], \
          hg_##kt##_2 = tab[2*32 + 2*8 + kt], hg_##kt##_3 = tab[2*32 + 3*8 + kt]; \
    asm volatile("" : "+a"(hr_##kt##_0), "+a"(hr_##kt##_1), "+a"(hr_##kt##_2), "+a"(hr_##kt##_3), \
                      "+a"(hz_##kt##_0), "+a"(hz_##kt##_1), "+a"(hz_##kt##_2), "+a"(hz_##kt##_3)); \
    asm volatile("" : "+v"(hg_##kt##_0), "+v"(hg_##kt##_1), "+v"(hg_##kt##_2), "+v"(hg_##kt##_3));

#define PA_KT(kt) { \
    half8 av = *(const half8*)(sH + abase + (((kt)*64 + rq*16) ^ asw)); \
    aR0 = MFMA16(av, hr_##kt##_0, aR0);  aZ0 = MFMA16(av, hz_##kt##_0, aZ0); \
    aR1 = MFMA16(av, hr_##kt##_1, aR1);  aZ1 = MFMA16(av, hz_##kt##_1, aZ1); \
    aR2 = MFMA16(av, hr_##kt##_2, aR2);  aZ2 = MFMA16(av, hz_##kt##_2, aZ2); \
    aR3 = MFMA16(av, hr_##kt##_3, aR3);  aZ3 = MFMA16(av, hz_##kt##_3, aZ3); }

#define PB_KT(kt) { \
    half8 av = *(const half8*)(sRH + abase + (((kt)*64 + rq*16) ^ asw)); \
    aG0 = MFMA16(av, hg_##kt##_0, aG0); \
    aG1 = MFMA16(av, hg_##kt##_1, aG1); \
    aG2 = MFMA16(av, hg_##kt##_2, aG2); \
    aG3 = MFMA16(av, hg_##kt##_3, aG3); }

#define EPIA(nti, AR, AZ, U0, U1, ZH, HV) { \
    const int col = (w * 4 + (nti)) * 16 + cl; \
    _Pragma("unroll") \
    for (int j = 0; j < 4; ++j) { \
        const int row = rq * 4 + j, e = ((nti) & 1) * 4 + j; \
        float r = __builtin_amdgcn_rcpf(1.f + __expf(-(AR[j] + (float)U0[e]))); \
        float z = __builtin_amdgcn_rcpf(1.f + __expf(-(AZ[j] + (float)U1[e]))); \
        ZH[e] = (f16)z; \
        *(f16*)(sRH + row * 512 + ((col * 2) ^ ((row & 7) << 4))) = (f16)(r * HV[j]); \
    } }

#define EPIB(nti, AG, U2, ZH, HV) { \
    const int col = (w * 4 + (nti)) * 16 + cl; \
    _Pragma("unroll") \
    for (int j = 0; j < 4; ++j) { \
        const int row = rq * 4 + j, e = ((nti) & 1) * 4 + j; \
        float ex = __expf(2.f * (AG[j] + (float)U2[e])); \
        float g = 1.f - 2.f * __builtin_amdgcn_rcpf(ex + 1.f); \
        float hn = HV[j] + (float)ZH[e] * (g - HV[j]); \
        HV[j] = hn; \
        *(f16*)(sH + row * 512 + ((col * 2) ^ ((row & 7) << 4))) = (f16)hn; \
        out[obase + (size_t)row * 131072 + col] = hn; \
    } }

__global__ __attribute__((amdgpu_waves_per_eu(1, 1))) void __launch_bounds__(256)
gru_scan4(const f16* __restrict__ ws, float* __restrict__ out) {
    extern __shared__ __align__(16) unsigned char smem[];
    unsigned char* sH  = smem;                // 8192  : h   f16 [16][256] swizzled
    unsigned char* sRH = smem + 8192;         // 8192  : r*h f16 [16][256] swizzled
    unsigned char* sU  = smem + 16384;        // 49152 : pre-gates [2][g3][w4][c2][lane64][16B]

    const int tid = threadIdx.x, w = tid >> 6, l = tid & 63;
    const int cl = l & 15, rq = l >> 4;
    const int blk = blockIdx.x, b0 = blk * 16;
    const unsigned char* wsb = (const unsigned char*)ws;

    // ---- weights: 96 named half8 per thread ----
    const half8* tab = (const half8*)(ws + RZG_OFF / 2) + (size_t)tid * 96;
    WLOAD(0) WLOAD(1) WLOAD(2) WLOAD(3) WLOAD(4) WLOAD(5) WLOAD(6) WLOAD(7)

    // ---- zero sH; zero out[:,0,:] ----
    { uint4 z = {}; ((uint4*)sH)[tid] = z; ((uint4*)sH)[256 + tid] = z; }
#pragma unroll
    for (int i = 0; i < 16; ++i) {
        int q = i * 256 + tid;
        out[(size_t)(b0 + (q >> 8)) * 131072 + (q & 255)] = 0.f;
    }

    // ---- preload sU buf0 with t=0 pre-gates ----
    {
        const unsigned char* src = wsb + PRE_OFF + (size_t)blk * 3 * 8192 + (size_t)(w * 64 + l) * 32;
        unsigned char* dst = sU + w * 2048;
#pragma unroll
        for (int g = 0; g < 3; ++g)
#pragma unroll
            for (int c = 0; c < 2; ++c)
                __builtin_amdgcn_global_load_lds((gp1)(const void*)(src + g * 8192 + c * 16),
                                                 (lp3)(void*)(dst + g * 8192 + c * 1024), 16, 0, 0);
    }

    float4 h0 = {}, h1 = {}, h2 = {}, h3 = {};   // master h (f32): h<nti>[j]

    asm volatile("s_waitcnt vmcnt(0) lgkmcnt(0)" ::: "memory");
    __builtin_amdgcn_s_barrier();
    __builtin_amdgcn_sched_barrier(0);

    const int abase = cl * 512;
    const int asw   = (cl & 7) << 4;

    for (int t = 0; t < 511; ++t) {
        const int buf = t & 1;
        const size_t obase = (size_t)b0 * 131072 + (size_t)(t + 1) * 256;

        // ---- phase A: R,Z pre-activations (A from sH, B from AGPRs) ----
        floatx4 aR0 = {}, aR1 = {}, aR2 = {}, aR3 = {};
        floatx4 aZ0 = {}, aZ1 = {}, aZ2 = {}, aZ3 = {};
        PA_KT(0) PA_KT(1) PA_KT(2) PA_KT(3) PA_KT(4) PA_KT(5) PA_KT(6) PA_KT(7)

        // ---- pre-gate stream: wait prev loads, issue next, read current ----
        asm volatile("s_waitcnt vmcnt(0)" ::: "memory");
        if (t < 510) {
            const unsigned char* src = wsb + PRE_OFF + (size_t)((t + 1) * 16 + blk) * 3 * 8192
                                       + (size_t)(w * 64 + l) * 32;
            unsigned char* dst = sU + (buf ^ 1) * 24576 + w * 2048;
#pragma unroll
            for (int g = 0; g < 3; ++g)
#pragma unroll
                for (int c = 0; c < 2; ++c)
                    __builtin_amdgcn_global_load_lds((gp1)(const void*)(src + g * 8192 + c * 16),
                                                     (lp3)(void*)(dst + g * 8192 + c * 1024), 16, 0, 0);
        }
        const unsigned char* ub = sU + buf * 24576 + w * 2048 + l * 16;
        half8 u0a = *(const half8*)(ub);
        half8 u0b = *(const half8*)(ub + 1024);
        half8 u1a = *(const half8*)(ub + 8192);
        half8 u1b = *(const half8*)(ub + 8192 + 1024);
        half8 u2a = *(const half8*)(ub + 16384);
        half8 u2b = *(const half8*)(ub + 16384 + 1024);

        // ---- epilogue A: r,z; write r*h to sRH; z saved as f16 ----
        half8 zsA = {}, zsB = {};
        EPIA(0, aR0, aZ0, u0a, u1a, zsA, h0)
        EPIA(1, aR1, aZ1, u0a, u1a, zsA, h1)
        EPIA(2, aR2, aZ2, u0b, u1b, zsB, h2)
        EPIA(3, aR3, aZ3, u0b, u1b, zsB, h3)

        asm volatile("s_waitcnt lgkmcnt(0)" ::: "memory");
        __builtin_amdgcn_s_barrier();
        __builtin_amdgcn_sched_barrier(0);

        // ---- phase B: G pre-activation (A from sRH, B from VGPRs) ----
        floatx4 aG0 = {}, aG1 = {}, aG2 = {}, aG3 = {};
        PB_KT(0) PB_KT(1) PB_KT(2) PB_KT(3) PB_KT(4) PB_KT(5) PB_KT(6) PB_KT(7)

        // ---- epilogue B: g=tanh, blend, write h to sH + out ----
        EPIB(0, aG0, u2a, zsA, h0)
        EPIB(1, aG1, u2a, zsA, h1)
        EPIB(2, aG2, u2b, zsB, h2)
        EPIB(3, aG3, u2b, zsB, h3)

        asm volatile("s_waitcnt lgkmcnt(0)" ::: "memory");
        __builtin_amdgcn_s_barrier();
        __builtin_amdgcn_sched_barrier(0);
    }
}

// =====================================================================
// v1 fallback (round-1 kernels, proven correct) — used if ws too small
// =====================================================================
__global__ void gru_prep(const float* __restrict__ Wr, const float* __restrict__ Wz,
                         const float* __restrict__ Wg, const float* __restrict__ Hr,
                         const float* __restrict__ Hz, const float* __restrict__ Hg,
                         f16* __restrict__ B) {
    int idx = blockIdx.x * 256 + threadIdx.x;
    int lane = idx & 63;
    int rest = idx >> 6;
    int kt = rest % 10;
    rest /= 10;
    int nt = rest & 15;
    int g  = rest >> 4;
    if (g >= 3) return;
    const float* H = (g == 0) ? Hr : (g == 1) ? Hz : Hg;
    const float* W = (g == 0) ? Wr : (g == 1) ? Wz : Wg;
    int col   = nt * 16 + (lane & 15);
    int kbase = kt * 32 + (lane >> 4) * 8;
    half8 v;
#pragma unroll
    for (int i = 0; i < 8; ++i) {
        int k = kbase + i;
        float val = (k < 256) ? H[k * 256 + col] : W[(k - 256) * 256 + col];
        v[i] = (f16)val;
    }
    *(half8*)(B + (size_t)idx * 8) = v;
}

__global__ void __launch_bounds__(512, 1)
gru_scan(const float* __restrict__ x,
         const float* __restrict__ br, const float* __restrict__ bz,
         const float* __restrict__ bg,
         const f16* __restrict__ Bfrag,
         float* __restrict__ out) {
    __shared__ __align__(16) unsigned char sH[8192];
    __shared__ __align__(16) unsigned char sRH[8192];
    __shared__ __align__(16) unsigned char sX[2][2048];

    const int tid  = threadIdx.x;
    const int wave = tid >> 6;
    const int lane = tid & 63;
    const int cl   = lane & 15;
    const int rq   = lane >> 4;
    const int b0   = blockIdx.x * 16;
    const int nt0  = wave * 2, nt1 = wave * 2 + 1;
    const int col0 = nt0 * 16 + cl, col1 = nt1 * 16 + cl;

    const int abase = cl * 512;
    const int asw   = (cl & 7) << 4;

    const float bR0 = br[col0], bR1 = br[col1];
    const float bZ0 = bz[col0], bZ1 = bz[col1];
    const float bG0 = bg[col0], bG1 = bg[col1];

    const half8* Bb  = (const half8*)Bfrag;
    const half8* pR0 = Bb + (size_t)((0 * 16 + nt0) * 10) * 64 + lane;
    const half8* pR1 = Bb + (size_t)((0 * 16 + nt1) * 10) * 64 + lane;
    const half8* pZ0 = Bb + (size_t)((1 * 16 + nt0) * 10) * 64 + lane;
    const half8* pZ1 = Bb + (size_t)((1 * 16 + nt1) * 10) * 64 + lane;
    const half8* pG0 = Bb + (size_t)((2 * 16 + nt0) * 10) * 64 + lane;
    const half8* pG1 = Bb + (size_t)((2 * 16 + nt1) * 10) * 64 + lane;

    float h0_[4] = {0.f, 0.f, 0.f, 0.f};
    float h1_[4] = {0.f, 0.f, 0.f, 0.f};
    float zs0[4], zs1[4];

    { half8 zz = {}; *(half8*)(sH + tid * 16) = zz; }
    for (int i = tid; i < 16 * 256; i += 512) {
        int r = i >> 8, c = i & 255;
        out[((size_t)(b0 + r) * 512) * 256 + c] = 0.f;
    }
    {
        size_t xo = (size_t)(b0 + wave) * 32768 + lane;
        float a0 = x[xo], a1 = x[xo + (size_t)8 * 32768];
        *(f16*)(sX[0] + wave * 128       + ((lane * 2) ^ ((wave & 7) << 4))) = (f16)a0;
        *(f16*)(sX[0] + (wave + 8) * 128 + ((lane * 2) ^ ((wave & 7) << 4))) = (f16)a1;
    }
    __syncthreads();

    for (int t = 0; t < 511; ++t) {
        const int xb = t & 1;
        float xp0 = 0.f, xp1 = 0.f;
        if (t < 510) {
            size_t xo = (size_t)(b0 + wave) * 32768 + (size_t)(t + 1) * 64 + lane;
            xp0 = x[xo];
            xp1 = x[xo + (size_t)8 * 32768];
        }

        floatx4 aR0 = {0,0,0,0}, aR1 = {0,0,0,0}, aZ0 = {0,0,0,0}, aZ1 = {0,0,0,0};
        half8 xa0, xa1;
#pragma unroll
        for (int kt = 0; kt < 8; ++kt) {
            half8 av = *(const half8*)(sH + abase + ((kt * 64 + rq * 16) ^ asw));
            aR0 = MFMA16(av, pR0[kt * 64], aR0);
            aR1 = MFMA16(av, pR1[kt * 64], aR1);
            aZ0 = MFMA16(av, pZ0[kt * 64], aZ0);
            aZ1 = MFMA16(av, pZ1[kt * 64], aZ1);
        }
        xa0 = *(const half8*)(sX[xb] + cl * 128 + ((rq * 16) ^ asw));
        xa1 = *(const half8*)(sX[xb] + cl * 128 + ((64 + rq * 16) ^ asw));
        aR0 = MFMA16(xa0, pR0[8 * 64], aR0);  aR1 = MFMA16(xa0, pR1[8 * 64], aR1);
        aZ0 = MFMA16(xa0, pZ0[8 * 64], aZ0);  aZ1 = MFMA16(xa0, pZ1[8 * 64], aZ1);
        aR0 = MFMA16(xa1, pR0[9 * 64], aR0);  aR1 = MFMA16(xa1, pR1[9 * 64], aR1);
        aZ0 = MFMA16(xa1, pZ0[9 * 64], aZ0);  aZ1 = MFMA16(xa1, pZ1[9 * 64], aZ1);

        if (t < 510) {
            const int nb = xb ^ 1;
            *(f16*)(sX[nb] + wave * 128       + ((lane * 2) ^ ((wave & 7) << 4))) = (f16)xp0;
            *(f16*)(sX[nb] + (wave + 8) * 128 + ((lane * 2) ^ ((wave & 7) << 4))) = (f16)xp1;
        }

#pragma unroll
        for (int j = 0; j < 4; ++j) {
            const int row = rq * 4 + j;
            float r0 = 1.f / (1.f + __expf(-(aR0[j] + bR0)));
            float r1 = 1.f / (1.f + __expf(-(aR1[j] + bR1)));
            zs0[j]   = 1.f / (1.f + __expf(-(aZ0[j] + bZ0)));
            zs1[j]   = 1.f / (1.f + __expf(-(aZ1[j] + bZ1)));
            const int sw = (row & 7) << 4;
            *(f16*)(sRH + row * 512 + ((col0 * 2) ^ sw)) = (f16)(r0 * h0_[j]);
            *(f16*)(sRH + row * 512 + ((col1 * 2) ^ sw)) = (f16)(r1 * h1_[j]);
        }
        __syncthreads();

        floatx4 aG0 = {0,0,0,0}, aG1 = {0,0,0,0};
#pragma unroll
        for (int kt = 0; kt < 8; ++kt) {
            half8 av = *(const half8*)(sRH + abase + ((kt * 64 + rq * 16) ^ asw));
            aG0 = MFMA16(av, pG0[kt * 64], aG0);
            aG1 = MFMA16(av, pG1[kt * 64], aG1);
        }
        aG0 = MFMA16(xa0, pG0[8 * 64], aG0);  aG1 = MFMA16(xa0, pG1[8 * 64], aG1);
        aG0 = MFMA16(xa1, pG0[9 * 64], aG0);  aG1 = MFMA16(xa1, pG1[9 * 64], aG1);

#pragma unroll
        for (int j = 0; j < 4; ++j) {
            const int row = rq * 4 + j;
            float e0 = __expf(2.f * (aG0[j] + bG0));
            float g0 = 1.f - 2.f / (e0 + 1.f);
            float e1 = __expf(2.f * (aG1[j] + bG1));
            float g1 = 1.f - 2.f / (e1 + 1.f);
            float hn0 = h0_[j] + zs0[j] * (g0 - h0_[j]);
            float hn1 = h1_[j] + zs1[j] * (g1 - h1_[j]);
            h0_[j] = hn0;
            h1_[j] = hn1;
            const int sw = (row & 7) << 4;
            *(f16*)(sH + row * 512 + ((col0 * 2) ^ sw)) = (f16)hn0;
            *(f16*)(sH + row * 512 + ((col1 * 2) ^ sw)) = (f16)hn1;
            size_t ob = ((size_t)(b0 + row) * 512 + (t + 1)) * 256;
            out[ob + col0] = hn0;
            out[ob + col1] = hn1;
        }
        __syncthreads();
    }
}

extern "C" void kernel_launch(void* const* d_in, const int* in_sizes, int n_in,
                              void* d_out, int out_size, void* d_ws, size_t ws_size,
                              hipStream_t stream) {
    const float* x  = (const float*)d_in[0];
    const float* Wr = (const float*)d_in[1];
    const float* br = (const float*)d_in[2];
    const float* Wz = (const float*)d_in[3];
    const float* bz = (const float*)d_in[4];
    const float* Wg = (const float*)d_in[5];
    const float* bg = (const float*)d_in[6];
    const float* Hr = (const float*)d_in[7];
    const float* Hz = (const float*)d_in[8];
    const float* Hg = (const float*)d_in[9];
    float* out = (float*)d_out;

    if (ws_size >= WS_NEED) {
        f16* ws = (f16*)d_ws;
        gru_wprep<<<120, 256, 0, stream>>>(Wr, Wz, Wg, Hr, Hz, Hg, ws);
        gru_gates<<<511 * 16, 256, 0, stream>>>(x, br, bz, bg, ws);
        (void)hipFuncSetAttribute((const void*)gru_scan4,
                                  hipFuncAttributeMaxDynamicSharedMemorySize, 65536);
        gru_scan4<<<16, 256, 65536, stream>>>(ws, out);
    } else {
        f16* Bfrag = (f16*)d_ws;
        gru_prep<<<120, 256, 0, stream>>>(Wr, Wz, Wg, Hr, Hz, Hg, Bfrag);
        gru_scan<<<16, 512, 0, stream>>>(x, br, bz, bg, Bfrag, out);
    }
}

// Round 6
// 1145.293 us; speedup vs baseline: 1.4373x; 1.4373x over previous
//
#include <hip/hip_runtime.h>
#include <hip/hip_bf16.h>

// GRU forward v6 — transposed MFMA epilogue, rz in AGPR, Hg in LDS.
//   Round-5 lesson: pinned regs + working set must leave slack vs the
//   256-reg/wave budget at 2 waves/SIMD (192+110 NaN'd). Round-3 re-read:
//   VGPR_Count excludes AGPRs -> v3's weights WERE resident (124 VGPR +
//   128 AGPR = 252); its 1.92us/step was LDS-instruction-bound
//   (~384 wave-instrs/step/CU, incl. 128 scalar ds_write_b16).
//   v6: compute P^T = H^T x h^T (weights = A-operand, h = B-operand).
//   Fragment layouts for weights/h are UNCHANGED; the D-fragment now gives
//   each thread 4 consecutive hidden cols of one batch row ->
//   epilogue LDS writes become 2x ds_write_b64 (was 8x b16) and out stores
//   2x float4 (was 8x f32). rz: 128 AGPR-pinned; Hg: 128KB LDS; budget
//   ~238/256 regs with slack.

typedef _Float16 f16;
typedef _Float16 half4 __attribute__((ext_vector_type(4)));
typedef _Float16 half8 __attribute__((ext_vector_type(8)));
typedef float floatx4 __attribute__((ext_vector_type(4)));

#define MFMA16(a, b, c) __builtin_amdgcn_mfma_f32_16x16x32_f16((a), (b), (c), 0, 0, 0)

// ---- workspace layout (bytes) ----
#define WTAB_OFF   0u          // W frags  [g3][nt16][ktx2][lane64][16B]      = 98304
#define RZTAB_OFF  98304u      // RZ frags [tid512][g2][nti2][kt8][16B]       = 262144
#define GTAB_OFF   360448u     // Hg frags [nt16][kt8][lane64][16B]           = 131072
#define PRE_OFF    491520u     // pre-gates [bid 8176][g3][tid512][16B]       = 200933376
#define WS_NEED    (491520ull + 200933376ull)

// =====================================================================
// prep: weight-fragment tables (unchanged from v3 — same layouts serve
// the transposed compute: frag(g,nt,ktx/kt,lane) = H[k][nt*16+(lane&15)])
// =====================================================================
__global__ void gru_wprep(const float* __restrict__ Wr, const float* __restrict__ Wz,
                          const float* __restrict__ Wg, const float* __restrict__ Hr,
                          const float* __restrict__ Hz, const float* __restrict__ Hg,
                          f16* __restrict__ ws) {
    int idx = blockIdx.x * 256 + threadIdx.x;   // 0..30719
    if (idx >= 30720) return;
    const float* src;
    int col, k0;
    f16* dst;
    if (idx < 6144) {                            // Wtab: ((g*16+nt)*2+ktx)*64+lane
        int lane = idx & 63, ktx = (idx >> 6) & 1, nt = (idx >> 7) & 15, g = idx >> 11;
        src = (g == 0) ? Wr : (g == 1) ? Wz : Wg;
        col = nt * 16 + (lane & 15);
        k0  = ktx * 32 + (lane >> 4) * 8;
        dst = ws + WTAB_OFF / 2 + (size_t)idx * 8;
    } else if (idx < 22528) {                    // RZtab: tid*32 + g*16 + nti*8 + kt
        int local = idx - 6144;
        int kt = local & 7, nti = (local >> 3) & 1, g = (local >> 4) & 1, tid = local >> 5;
        int w = tid >> 6, l = tid & 63;
        src = g ? Hz : Hr;
        col = (w * 2 + nti) * 16 + (l & 15);
        k0  = kt * 32 + (l >> 4) * 8;
        dst = ws + RZTAB_OFF / 2 + (size_t)local * 8;
    } else {                                     // Gtab: (nt*8+kt)*64+lane
        int local = idx - 22528;                 // 0..8191
        int lane = local & 63, q = local >> 6;
        int kt = q & 7, nt = q >> 3;
        src = Hg;
        col = nt * 16 + (lane & 15);
        k0  = kt * 32 + (lane >> 4) * 8;
        dst = ws + GTAB_OFF / 2 + (size_t)local * 8;
    }
    half8 v;
#pragma unroll
    for (int i = 0; i < 8; ++i) v[i] = (f16)src[(size_t)(k0 + i) * 256 + col];
    *(half8*)dst = v;
}

// =====================================================================
// prep: pre-gates (transposed MFMA: A=W-frag, B=x-frag).
//   Thread owns (m = l&15, n = (w*2+nti)*16 + rq*4 + j).
//   pre[bid][g][tid] half8, elem nti*4+j.
// =====================================================================
__global__ void __launch_bounds__(512)
gru_gates(const float* __restrict__ x, const float* __restrict__ br,
          const float* __restrict__ bz, const float* __restrict__ bg,
          f16* __restrict__ ws) {
    const int bid = blockIdx.x;                  // t*16 + blk, t in [0,511)
    const int t = bid >> 4, blk = bid & 15;
    const int tid = threadIdx.x, w = tid >> 6, l = tid & 63;
    const int m = l & 15, rq = l >> 4;

    // B-operand x-frags: x[blk*16+m][t*64 + ktx*32 + rq*8 + i]
    half8 xb[2];
    const float* xr = x + (size_t)(blk * 16 + m) * 32768 + (size_t)t * 64 + rq * 8;
#pragma unroll
    for (int ktx = 0; ktx < 2; ++ktx) {
        float4 a = *(const float4*)(xr + ktx * 32);
        float4 b = *(const float4*)(xr + ktx * 32 + 4);
        half8 v;
        v[0] = (f16)a.x; v[1] = (f16)a.y; v[2] = (f16)a.z; v[3] = (f16)a.w;
        v[4] = (f16)b.x; v[5] = (f16)b.y; v[6] = (f16)b.z; v[7] = (f16)b.w;
        xb[ktx] = v;
    }

    const half8* Wt = (const half8*)(ws + WTAB_OFF / 2);
    floatx4 acc[3][2];
#pragma unroll
    for (int g = 0; g < 3; ++g)
#pragma unroll
        for (int nti = 0; nti < 2; ++nti) {
            int n0 = (w * 2 + nti) * 16 + rq * 4;
            float4 bv = *(const float4*)((g == 0 ? br : g == 1 ? bz : bg) + n0);
            acc[g][nti] = (floatx4){bv.x, bv.y, bv.z, bv.w};
        }
#pragma unroll
    for (int g = 0; g < 3; ++g)
#pragma unroll
        for (int nti = 0; nti < 2; ++nti) {
            int nt = w * 2 + nti;
#pragma unroll
            for (int ktx = 0; ktx < 2; ++ktx)
                acc[g][nti] = MFMA16(Wt[(size_t)((g * 16 + nt) * 2 + ktx) * 64 + l], xb[ktx],
                                     acc[g][nti]);
        }

    half8* preb = (half8*)(ws + PRE_OFF / 2);
#pragma unroll
    for (int g = 0; g < 3; ++g) {
        half8 v;
#pragma unroll
        for (int nti = 0; nti < 2; ++nti)
#pragma unroll
            for (int j = 0; j < 4; ++j)
                v[nti * 4 + j] = (f16)acc[g][nti][j];
        preb[((size_t)bid * 3 + g) * 512 + tid] = v;
    }
}

// =====================================================================
// scan v6: 16 WGs x 512 threads (8 waves, 2/SIMD)
//   rz: 128 AGPR-pinned regs/thread; Hg: LDS. Transposed epilogue.
// =====================================================================

#define WLOAD6(kt) \
    half8 hr_##kt##_0 = rzt[kt],      hr_##kt##_1 = rzt[8 + kt];  \
    half8 hz_##kt##_0 = rzt[16 + kt], hz_##kt##_1 = rzt[24 + kt]; \
    asm volatile("" : "+a"(hr_##kt##_0), "+a"(hr_##kt##_1), \
                      "+a"(hz_##kt##_0), "+a"(hz_##kt##_1));

#define PA6(kt) { \
    half8 hv = *(const half8*)(sH + hbase + (((kt) * 64 + rq * 16) ^ hsw)); \
    aR0 = MFMA16(hr_##kt##_0, hv, aR0);  aZ0 = MFMA16(hz_##kt##_0, hv, aZ0); \
    aR1 = MFMA16(hr_##kt##_1, hv, aR1);  aZ1 = MFMA16(hz_##kt##_1, hv, aZ1); }

#define PB6(kt) { \
    half8 hv = *(const half8*)(sRH + hbase + (((kt) * 64 + rq * 16) ^ hsw)); \
    half8 bf0 = *(const half8*)(sG + (size_t)(((nt0 * 8 + (kt)) * 64 + l)) * 16); \
    half8 bf1 = *(const half8*)(sG + (size_t)(((nt1 * 8 + (kt)) * 64 + l)) * 16); \
    aG0 = MFMA16(bf0, hv, aG0); \
    aG1 = MFMA16(bf1, hv, aG1); }

__global__ void __launch_bounds__(512, 2)
gru_scan6(const f16* __restrict__ ws, float* __restrict__ out) {
    extern __shared__ __align__(16) unsigned char smem[];
    unsigned char* sH  = smem;               // 8192   : h   f16 [16][256] swizzled
    unsigned char* sRH = smem + 8192;        // 8192   : r*h f16 [16][256] swizzled
    unsigned char* sG  = smem + 16384;       // 131072 : Hg frags [nt16][kt8][lane64][16B]

    const int tid = threadIdx.x, w = tid >> 6, l = tid & 63;
    const int m = l & 15, rq = l >> 4;
    const int blk = blockIdx.x, b0 = blk * 16;
    const int nt0 = w * 2, nt1 = w * 2 + 1;
    const int n0a = nt0 * 16 + rq * 4;       // 4 consecutive hidden cols (nti=0)
    const int n0b = nt1 * 16 + rq * 4;       // 4 consecutive hidden cols (nti=1)

    // ---- rz weights: 32 named half8/thread, AGPR-pinned (128 AGPRs) ----
    const half8* rzt = (const half8*)(ws + RZTAB_OFF / 2) + (size_t)tid * 32;
    WLOAD6(0) WLOAD6(1) WLOAD6(2) WLOAD6(3) WLOAD6(4) WLOAD6(5) WLOAD6(6) WLOAD6(7)

    // ---- stage Hg into LDS (128KB) ----
    {
        const uint4* src = (const uint4*)(ws + GTAB_OFF / 2);
        uint4* dst = (uint4*)sG;
#pragma unroll
        for (int i = 0; i < 16; ++i) dst[tid + i * 512] = src[tid + i * 512];
    }
    // ---- zero sH; zero out[:,0,:] ----
    { uint4 z = {}; ((uint4*)sH)[tid] = z; }
#pragma unroll
    for (int i = 0; i < 8; ++i) {
        int q = i * 512 + tid;
        out[(size_t)(b0 + (q >> 8)) * 131072 + (q & 255)] = 0.f;
    }

    float h[2][4] = {};      // h at (m, n0a+j) and (m, n0b+j)
    float zs[2][4];

    const half8* preb = (const half8*)(ws + PRE_OFF / 2);
    half8 ucur[3], unxt[3] = {};
#pragma unroll
    for (int g = 0; g < 3; ++g)
        ucur[g] = preb[((size_t)blk * 3 + g) * 512 + tid];

    asm volatile("s_waitcnt lgkmcnt(0)" ::: "memory");
    __builtin_amdgcn_s_barrier();
    __builtin_amdgcn_sched_barrier(0);

    const int hbase = m * 512;           // h row stride 512B
    const int hsw   = (m & 7) << 4;      // XOR swizzle for this row
    const int wbA   = hbase + ((n0a * 2) ^ hsw);   // byte addr of this thread's 8B slot
    const int wbB   = hbase + ((n0b * 2) ^ hsw);

    for (int t = 0; t < 511; ++t) {
        // prefetch next step's gates into registers (counted vmcnt, no drain)
        if (t < 510) {
            const half8* p = preb + ((size_t)((t + 1) * 16 + blk) * 3) * 512 + tid;
#pragma unroll
            for (int g = 0; g < 3; ++g) unxt[g] = p[g * 512];
        }

        // ---- phase A: R,Z pre-activations (A=rz from AGPR, B=h from sH) ----
        floatx4 aR0 = {}, aR1 = {}, aZ0 = {}, aZ1 = {};
        PA6(0) PA6(1) PA6(2) PA6(3) PA6(4) PA6(5) PA6(6) PA6(7)

        // ---- epilogue A: r,z; write r*h (half4, one b64 per nti) ----
        {
            half4 p0, p1;
#pragma unroll
            for (int j = 0; j < 4; ++j) {
                float r0 = __builtin_amdgcn_rcpf(1.f + __expf(-(aR0[j] + (float)ucur[0][j])));
                float z0 = __builtin_amdgcn_rcpf(1.f + __expf(-(aZ0[j] + (float)ucur[1][j])));
                float r1 = __builtin_amdgcn_rcpf(1.f + __expf(-(aR1[j] + (float)ucur[0][4 + j])));
                float z1 = __builtin_amdgcn_rcpf(1.f + __expf(-(aZ1[j] + (float)ucur[1][4 + j])));
                zs[0][j] = z0;  zs[1][j] = z1;
                p0[j] = (f16)(r0 * h[0][j]);
                p1[j] = (f16)(r1 * h[1][j]);
            }
            *(half4*)(sRH + wbA) = p0;
            *(half4*)(sRH + wbB) = p1;
        }
        asm volatile("s_waitcnt lgkmcnt(0)" ::: "memory");
        __builtin_amdgcn_s_barrier();
        __builtin_amdgcn_sched_barrier(0);

        // ---- phase B: G pre-activation (A=Hg from sG, B=rh from sRH) ----
        floatx4 aG0 = {}, aG1 = {};
        PB6(0) PB6(1) PB6(2) PB6(3) PB6(4) PB6(5) PB6(6) PB6(7)

        // ---- epilogue B: g=tanh, blend, write h (b64) + out (float4) ----
        {
            half4 p0, p1;
            float4 o0, o1;
#pragma unroll
            for (int j = 0; j < 4; ++j) {
                float e0 = __expf(2.f * (aG0[j] + (float)ucur[2][j]));
                float g0 = 1.f - 2.f * __builtin_amdgcn_rcpf(e0 + 1.f);   // tanh, inf-safe
                float e1 = __expf(2.f * (aG1[j] + (float)ucur[2][4 + j]));
                float g1 = 1.f - 2.f * __builtin_amdgcn_rcpf(e1 + 1.f);
                float hn0 = h[0][j] + zs[0][j] * (g0 - h[0][j]);
                float hn1 = h[1][j] + zs[1][j] * (g1 - h[1][j]);
                h[0][j] = hn0;  h[1][j] = hn1;
                p0[j] = (f16)hn0;  p1[j] = (f16)hn1;
                ((float*)&o0)[j] = hn0;  ((float*)&o1)[j] = hn1;
            }
            *(half4*)(sH + wbA) = p0;
            *(half4*)(sH + wbB) = p1;
            float* ob = out + (size_t)(b0 + m) * 131072 + (size_t)(t + 1) * 256;
            *(float4*)(ob + n0a) = o0;
            *(float4*)(ob + n0b) = o1;
        }
#pragma unroll
        for (int g = 0; g < 3; ++g) ucur[g] = unxt[g];
        asm volatile("s_waitcnt lgkmcnt(0)" ::: "memory");
        __builtin_amdgcn_s_barrier();
        __builtin_amdgcn_sched_barrier(0);
    }
}

// =====================================================================
// v1 fallback (round-1 kernels, proven correct) — used if ws too small
// =====================================================================
__global__ void gru_prep(const float* __restrict__ Wr, const float* __restrict__ Wz,
                         const float* __restrict__ Wg, const float* __restrict__ Hr,
                         const float* __restrict__ Hz, const float* __restrict__ Hg,
                         f16* __restrict__ B) {
    int idx = blockIdx.x * 256 + threadIdx.x;
    int lane = idx & 63;
    int rest = idx >> 6;
    int kt = rest % 10;
    rest /= 10;
    int nt = rest & 15;
    int g  = rest >> 4;
    if (g >= 3) return;
    const float* H = (g == 0) ? Hr : (g == 1) ? Hz : Hg;
    const float* W = (g == 0) ? Wr : (g == 1) ? Wz : Wg;
    int col   = nt * 16 + (lane & 15);
    int kbase = kt * 32 + (lane >> 4) * 8;
    half8 v;
#pragma unroll
    for (int i = 0; i < 8; ++i) {
        int k = kbase + i;
        float val = (k < 256) ? H[k * 256 + col] : W[(k - 256) * 256 + col];
        v[i] = (f16)val;
    }
    *(half8*)(B + (size_t)idx * 8) = v;
}

__global__ void __launch_bounds__(512, 1)
gru_scan(const float* __restrict__ x,
         const float* __restrict__ br, const float* __restrict__ bz,
         const float* __restrict__ bg,
         const f16* __restrict__ Bfrag,
         float* __restrict__ out) {
    __shared__ __align__(16) unsigned char sH[8192];
    __shared__ __align__(16) unsigned char sRH[8192];
    __shared__ __align__(16) unsigned char sX[2][2048];

    const int tid  = threadIdx.x;
    const int wave = tid >> 6;
    const int lane = tid & 63;
    const int cl   = lane & 15;
    const int rq   = lane >> 4;
    const int b0   = blockIdx.x * 16;
    const int nt0  = wave * 2, nt1 = wave * 2 + 1;
    const int col0 = nt0 * 16 + cl, col1 = nt1 * 16 + cl;

    const int abase = cl * 512;
    const int asw   = (cl & 7) << 4;

    const float bR0 = br[col0], bR1 = br[col1];
    const float bZ0 = bz[col0], bZ1 = bz[col1];
    const float bG0 = bg[col0], bG1 = bg[col1];

    const half8* Bb  = (const half8*)Bfrag;
    const half8* pR0 = Bb + (size_t)((0 * 16 + nt0) * 10) * 64 + lane;
    const half8* pR1 = Bb + (size_t)((0 * 16 + nt1) * 10) * 64 + lane;
    const half8* pZ0 = Bb + (size_t)((1 * 16 + nt0) * 10) * 64 + lane;
    const half8* pZ1 = Bb + (size_t)((1 * 16 + nt1) * 10) * 64 + lane;
    const half8* pG0 = Bb + (size_t)((2 * 16 + nt0) * 10) * 64 + lane;
    const half8* pG1 = Bb + (size_t)((2 * 16 + nt1) * 10) * 64 + lane;

    float h0_[4] = {0.f, 0.f, 0.f, 0.f};
    float h1_[4] = {0.f, 0.f, 0.f, 0.f};
    float zs0[4], zs1[4];

    { half8 zz = {}; *(half8*)(sH + tid * 16) = zz; }
    for (int i = tid; i < 16 * 256; i += 512) {
        int r = i >> 8, c = i & 255;
        out[((size_t)(b0 + r) * 512) * 256 + c] = 0.f;
    }
    {
        size_t xo = (size_t)(b0 + wave) * 32768 + lane;
        float a0 = x[xo], a1 = x[xo + (size_t)8 * 32768];
        *(f16*)(sX[0] + wave * 128       + ((lane * 2) ^ ((wave & 7) << 4))) = (f16)a0;
        *(f16*)(sX[0] + (wave + 8) * 128 + ((lane * 2) ^ ((wave & 7) << 4))) = (f16)a1;
    }
    __syncthreads();

    for (int t = 0; t < 511; ++t) {
        const int xb = t & 1;
        float xp0 = 0.f, xp1 = 0.f;
        if (t < 510) {
            size_t xo = (size_t)(b0 + wave) * 32768 + (size_t)(t + 1) * 64 + lane;
            xp0 = x[xo];
            xp1 = x[xo + (size_t)8 * 32768];
        }

        floatx4 aR0 = {0,0,0,0}, aR1 = {0,0,0,0}, aZ0 = {0,0,0,0}, aZ1 = {0,0,0,0};
        half8 xa0, xa1;
#pragma unroll
        for (int kt = 0; kt < 8; ++kt) {
            half8 av = *(const half8*)(sH + abase + ((kt * 64 + rq * 16) ^ asw));
            aR0 = MFMA16(av, pR0[kt * 64], aR0);
            aR1 = MFMA16(av, pR1[kt * 64], aR1);
            aZ0 = MFMA16(av, pZ0[kt * 64], aZ0);
            aZ1 = MFMA16(av, pZ1[kt * 64], aZ1);
        }
        xa0 = *(const half8*)(sX[xb] + cl * 128 + ((rq * 16) ^ asw));
        xa1 = *(const half8*)(sX[xb] + cl * 128 + ((64 + rq * 16) ^ asw));
        aR0 = MFMA16(xa0, pR0[8 * 64], aR0);  aR1 = MFMA16(xa0, pR1[8 * 64], aR1);
        aZ0 = MFMA16(xa0, pZ0[8 * 64], aZ0);  aZ1 = MFMA16(xa0, pZ1[8 * 64], aZ1);
        aR0 = MFMA16(xa1, pR0[9 * 64], aR0);  aR1 = MFMA16(xa1, pR1[9 * 64], aR1);
        aZ0 = MFMA16(xa1, pZ0[9 * 64], aZ0);  aZ1 = MFMA16(xa1, pZ1[9 * 64], aZ1);

        if (t < 510) {
            const int nb = xb ^ 1;
            *(f16*)(sX[nb] + wave * 128       + ((lane * 2) ^ ((wave & 7) << 4))) = (f16)xp0;
            *(f16*)(sX[nb] + (wave + 8) * 128 + ((lane * 2) ^ ((wave & 7) << 4))) = (f16)xp1;
        }

#pragma unroll
        for (int j = 0; j < 4; ++j) {
            const int row = rq * 4 + j;
            float r0 = 1.f / (1.f + __expf(-(aR0[j] + bR0)));
            float r1 = 1.f / (1.f + __expf(-(aR1[j] + bR1)));
            zs0[j]   = 1.f / (1.f + __expf(-(aZ0[j] + bZ0)));
            zs1[j]   = 1.f / (1.f + __expf(-(aZ1[j] + bZ1)));
            const int sw = (row & 7) << 4;
            *(f16*)(sRH + row * 512 + ((col0 * 2) ^ sw)) = (f16)(r0 * h0_[j]);
            *(f16*)(sRH + row * 512 + ((col1 * 2) ^ sw)) = (f16)(r1 * h1_[j]);
        }
        __syncthreads();

        floatx4 aG0 = {0,0,0,0}, aG1 = {0,0,0,0};
#pragma unroll
        for (int kt = 0; kt < 8; ++kt) {
            half8 av = *(const half8*)(sRH + abase + ((kt * 64 + rq * 16) ^ asw));
            aG0 = MFMA16(av, pG0[kt * 64], aG0);
            aG1 = MFMA16(av, pG1[kt * 64], aG1);
        }
        aG0 = MFMA16(xa0, pG0[8 * 64], aG0);  aG1 = MFMA16(xa0, pG1[8 * 64], aG1);
        aG0 = MFMA16(xa1, pG0[9 * 64], aG0);  aG1 = MFMA16(xa1, pG1[9 * 64], aG1);

#pragma unroll
        for (int j = 0; j < 4; ++j) {
            const int row = rq * 4 + j;
            float e0 = __expf(2.f * (aG0[j] + bG0));
            float g0 = 1.f - 2.f / (e0 + 1.f);
            float e1 = __expf(2.f * (aG1[j] + bG1));
            float g1 = 1.f - 2.f / (e1 + 1.f);
            float hn0 = h0_[j] + zs0[j] * (g0 - h0_[j]);
            float hn1 = h1_[j] + zs1[j] * (g1 - h1_[j]);
            h0_[j] = hn0;
            h1_[j] = hn1;
            const int sw = (row & 7) << 4;
            *(f16*)(sH + row * 512 + ((col0 * 2) ^ sw)) = (f16)hn0;
            *(f16*)(sH + row * 512 + ((col1 * 2) ^ sw)) = (f16)hn1;
            size_t ob = ((size_t)(b0 + row) * 512 + (t + 1)) * 256;
            out[ob + col0] = hn0;
            out[ob + col1] = hn1;
        }
        __syncthreads();
    }
}

extern "C" void kernel_launch(void* const* d_in, const int* in_sizes, int n_in,
                              void* d_out, int out_size, void* d_ws, size_t ws_size,
                              hipStream_t stream) {
    const float* x  = (const float*)d_in[0];
    const float* Wr = (const float*)d_in[1];
    const float* br = (const float*)d_in[2];
    const float* Wz = (const float*)d_in[3];
    const float* bz = (const float*)d_in[4];
    const float* Wg = (const float*)d_in[5];
    const float* bg = (const float*)d_in[6];
    const float* Hr = (const float*)d_in[7];
    const float* Hz = (const float*)d_in[8];
    const float* Hg = (const float*)d_in[9];
    float* out = (float*)d_out;

    if (ws_size >= WS_NEED) {
        f16* ws = (f16*)d_ws;
        gru_wprep<<<120, 256, 0, stream>>>(Wr, Wz, Wg, Hr, Hz, Hg, ws);
        gru_gates<<<511 * 16, 512, 0, stream>>>(x, br, bz, bg, ws);
        (void)hipFuncSetAttribute((const void*)gru_scan6,
                                  hipFuncAttributeMaxDynamicSharedMemorySize, 147456);
        gru_scan6<<<16, 512, 147456, stream>>>(ws, out);
    } else {
        f16* Bfrag = (f16*)d_ws;
        gru_prep<<<120, 256, 0, stream>>>(Wr, Wz, Wg, Hr, Hz, Hg, Bfrag);
        gru_scan<<<16, 512, 0, stream>>>(x, br, bz, bg, Bfrag, out);
    }
}